// Round 11
// baseline (255.104 us; speedup 1.0000x reference)
//
#include <hip/hip_runtime.h>
#include <hip/hip_bf16.h>

// Problem constants
#define B_ 4
#define T_ 2048
#define D_ 1024
#define H_ 16
#define HD_ 64
#define M_ (B_ * T_)   // 8192 rows

typedef __attribute__((ext_vector_type(8))) short   s16x8;
typedef __attribute__((ext_vector_type(4))) short   s16x4;
typedef __attribute__((ext_vector_type(4))) float   f32x4;
typedef __attribute__((ext_vector_type(4))) float   fvec4;
typedef __attribute__((ext_vector_type(4))) unsigned short u16x4;

union U4 { u16x4 v; unsigned int w[2]; };
union P8 { s16x8 v; unsigned int w[4]; };

// pack two fp32 -> one dword of 2 bf16 (RNE) via HW instr (no builtin on gfx950)
__device__ inline unsigned int pk_bf16(float a, float b) {
    unsigned int r;
    asm("v_cvt_pk_bf16_f32 %0, %1, %2" : "=v"(r) : "v"(a), "v"(b));
    return r;
}

__device__ inline f32x4 mfma32(s16x8 a, s16x8 b, f32x4 c) {
    return __builtin_amdgcn_mfma_f32_16x16x32_bf16(a, b, c, 0, 0, 0);
}

// async global->LDS, 16B/lane; LDS dest = wave-uniform base + lane*16
__device__ inline void gld16(const unsigned short* g, unsigned short* l) {
    __builtin_amdgcn_global_load_lds(
        (const __attribute__((address_space(1))) unsigned int*)g,
        (__attribute__((address_space(3))) unsigned int*)l, 16, 0, 0);
}

// ---------------------------------------------------------------------------
// Fused fp32->bf16 convert: 8 elems/thread (2x fvec4 -> 2x u16x4), grid 6144.
// x: 4096 blocks; each weight: 512 blocks.
// ---------------------------------------------------------------------------
__global__ void cvt_all(const float* __restrict__ x,
                        const float* __restrict__ wq, const float* __restrict__ wk,
                        const float* __restrict__ wv, const float* __restrict__ wo,
                        unsigned short* __restrict__ xb, unsigned short* __restrict__ wcat) {
    const int bid = blockIdx.x;
    const float* src; unsigned short* dst; int off;
    if (bid < 4096)      { src = x;  dst = xb;                 off = bid; }
    else if (bid < 4608) { src = wq; dst = wcat;               off = bid - 4096; }
    else if (bid < 5120) { src = wk; dst = wcat + 1 * 1048576; off = bid - 4608; }
    else if (bid < 5632) { src = wv; dst = wcat + 2 * 1048576; off = bid - 5120; }
    else                 { src = wo; dst = wcat + 3 * 1048576; off = bid - 5632; }
    int i = off * 2048 + threadIdx.x * 8;
    fvec4 v0 = *(const fvec4*)(src + i);
    fvec4 v1 = *(const fvec4*)(src + i + 4);
    U4 o0, o1;
    o0.w[0] = pk_bf16(v0[0], v0[1]);  o0.w[1] = pk_bf16(v0[2], v0[3]);
    o1.w[0] = pk_bf16(v1[0], v1[1]);  o1.w[1] = pk_bf16(v1[2], v1[3]);
    *(u16x4*)(dst + i) = o0.v;
    *(u16x4*)(dst + i + 4) = o1.v;
}

// ---------------------------------------------------------------------------
// GEMM core: 128x128 tile, BK=32, gld16 staging, FULLY UNROLLED K-loop.
// Triple-buffer + counted vmcnt(4); conflict-free chunk-XOR staging.
// R10: fragment ds_reads issued BEFORE the prefetch STG (reads buffer rb,
// STG writes buffer (c+2)%3 -- disjoint, so the reorder is semantically
// free and lets the MFMAs' lgkmcnt deps resolve sooner).
// ---------------------------------------------------------------------------
__device__ __forceinline__ void gemm_core(
    const unsigned short* __restrict__ P0, const unsigned short* __restrict__ P1,
    int o0, int o1, int tid, unsigned short* As, unsigned short* Bs,
    f32x4 acc[4][4]) {
    const int lane = tid & 63, wave = tid >> 6;
    const int quad = lane >> 4, l16 = lane & 15;
    const int wr = (wave >> 1) * 64, wc = (wave & 1) * 64;
    const int sxo = (quad ^ ((l16 >> 1) & 3)) * 8;

    const int row0 = tid >> 2;
    const int c8 = ((tid & 3) ^ ((tid >> 3) & 3)) * 8;
    const unsigned short* gA0 = P0 + (size_t)(o0 + row0) * 1024 + c8;
    const unsigned short* gA1 = gA0 + 64 * 1024;
    const unsigned short* gB0 = P1 + (size_t)(o1 + row0) * 1024 + c8;
    const unsigned short* gB1 = gB0 + 64 * 1024;
    unsigned short* dA = As + tid * 8;
    unsigned short* dB = Bs + tid * 8;

    const unsigned short* rA = As + (wr + l16) * 32 + sxo;
    const unsigned short* rB = Bs + (wc + l16) * 32 + sxo;

#define STG(buf_, kn_) do {                                   \
        gld16(gA0 + (kn_), dA + (buf_) * 4096);               \
        gld16(gA1 + (kn_), dA + (buf_) * 4096 + 2048);        \
        gld16(gB0 + (kn_), dB + (buf_) * 4096);               \
        gld16(gB1 + (kn_), dB + (buf_) * 4096 + 2048);        \
    } while (0)

    STG(0, 0);
    STG(1, 32);

#pragma unroll
    for (int c = 0; c < 32; ++c) {
        if (c < 31) { asm volatile("s_waitcnt vmcnt(4)" ::: "memory"); }
        else        { asm volatile("s_waitcnt vmcnt(0)" ::: "memory"); }
        __builtin_amdgcn_s_barrier();
        const int rb = c % 3;                      // compile-time after unroll
        s16x8 af[4], bfr[4];
        for (int i = 0; i < 4; ++i)
            af[i] = *(const s16x8*)(rA + rb * 4096 + i * 512);
        for (int j = 0; j < 4; ++j)
            bfr[j] = *(const s16x8*)(rB + rb * 4096 + j * 512);
        if (c + 2 < 32) { STG((c + 2) % 3, (c + 2) * 32); }
        __builtin_amdgcn_s_setprio(1);
        for (int i = 0; i < 4; ++i)
            for (int j = 0; j < 4; ++j)
                acc[i][j] = mfma32(af[i], bfr[j], acc[i][j]);
        __builtin_amdgcn_s_setprio(0);
    }
#undef STG
}

// Fused Q/K/V projection: 1-D grid 1536, XCD-chunked for A-panel L2 reuse.
__global__ __launch_bounds__(256) void gemm_qkv(
    const unsigned short* __restrict__ A, const unsigned short* __restrict__ Wcat,
    const float* __restrict__ bq, const float* __restrict__ bk, const float* __restrict__ bv,
    unsigned short* __restrict__ Qb, unsigned short* __restrict__ Kb,
    unsigned short* __restrict__ Vt, float qscale) {
    __shared__ __align__(16) unsigned short As[3 * 4096];
    __shared__ __align__(16) unsigned short Bs[3 * 4096];
    const int flat = blockIdx.x;
    const int j = flat >> 3;
    const int mt = (flat & 7) * 8 + (j & 7);          // 0..63
    const int y  = j >> 3;                            // 0..23
    const int proj = y >> 3;
    const int m0 = mt * 128, n0 = (y & 7) * 128;
    const unsigned short* W = Wcat + (size_t)proj * 1048576;
    const float* bias = proj == 0 ? bq : (proj == 1 ? bk : bv);

    const int tid = threadIdx.x;
    const int lane = tid & 63, wave = tid >> 6;
    const int quad = lane >> 4, l16 = lane & 15;
    const int wr = (wave >> 1) * 64, wc = (wave & 1) * 64;

    f32x4 acc[4][4] = {};

    if (proj != 2) {
        // swapped: first operand = W (n-dim at wr), second = A (m-dim at wc)
        gemm_core(W, A, n0, m0, tid, As, Bs, acc);
        const float scale = (proj == 0) ? qscale : 1.0f;
        unsigned short* outp = (proj == 0) ? Qb : Kb;
        for (int jj = 0; jj < 4; ++jj) {
            int t = m0 + wc + jj * 16 + l16;           // token per lane
            int b = t >> 11, tt = t & (T_ - 1);
            for (int i = 0; i < 4; ++i) {
                int nb = n0 + wr + i * 16 + quad * 4;  // 4 consecutive out cols
                fvec4 bi = *(const fvec4*)(bias + nb);
                int h = nb >> 6, hd = nb & 63;
                float v0 = (acc[i][jj][0] + bi[0]) * scale;
                float v1 = (acc[i][jj][1] + bi[1]) * scale;
                float v2 = (acc[i][jj][2] + bi[2]) * scale;
                float v3 = (acc[i][jj][3] + bi[3]) * scale;
                U4 o;
                o.w[0] = pk_bf16(v0, v1);
                o.w[1] = pk_bf16(v2, v3);
                *(u16x4*)(outp + ((size_t)(b * H_ + h) * T_ + tt) * HD_ + hd) = o.v;
            }
        }
    } else {
        // normal: first operand = A (m-dim at wr), second = W (n-dim at wc)
        gemm_core(A, W, m0, n0, tid, As, Bs, acc);
        for (int i = 0; i < 4; ++i) {
            int mbase = m0 + wr + i * 16 + quad * 4;   // 4 consecutive t, same b
            int b = mbase >> 11, t = mbase & (T_ - 1);
            // t&3 == 0; permuted position (still 4 consecutive slots)
            int tp = (t & ~31) | (((t >> 2) & 3) << 3) | (((t >> 4) & 1) << 2);
            for (int jj = 0; jj < 4; ++jj) {
                int n = n0 + wc + jj * 16 + l16;
                float bi = bias[n];
                int h = n >> 6, hd = n & 63;
                U4 o;
                o.w[0] = pk_bf16(acc[i][jj][0] + bi, acc[i][jj][1] + bi);
                o.w[1] = pk_bf16(acc[i][jj][2] + bi, acc[i][jj][3] + bi);
                *(u16x4*)(Vt + ((size_t)(b * H_ + h) * HD_ + hd) * T_ + tp) = o.v;
            }
        }
    }
}

// Output projection: fp32 row-major out.  1-D grid 512, same XCD chunking.
__global__ __launch_bounds__(256) void gemm_o(
    const unsigned short* __restrict__ A, const unsigned short* __restrict__ W,
    const float* __restrict__ bias, float* __restrict__ out) {
    __shared__ __align__(16) unsigned short As[3 * 4096];
    __shared__ __align__(16) unsigned short Bs[3 * 4096];
    const int flat = blockIdx.x;
    const int j = flat >> 3;
    const int m0 = ((flat & 7) * 8 + (j & 7)) * 128;
    const int n0 = (j >> 3) * 128;                    // 0..7

    const int tid = threadIdx.x;
    const int lane = tid & 63, wave = tid >> 6;
    const int quad = lane >> 4, l16 = lane & 15;
    const int wr = (wave >> 1) * 64, wc = (wave & 1) * 64;

    f32x4 acc[4][4] = {};
    gemm_core(W, A, n0, m0, tid, As, Bs, acc);        // swapped

    for (int jj = 0; jj < 4; ++jj) {
        int m = m0 + wc + jj * 16 + l16;
        for (int i = 0; i < 4; ++i) {
            int nb = n0 + wr + i * 16 + quad * 4;
            fvec4 bi = *(const fvec4*)(bias + nb);
            fvec4 o = acc[i][jj] + bi;
            *(fvec4*)(out + (size_t)m * D_ + nb) = o;
        }
    }
}

// ---------------------------------------------------------------------------
// Flash attention, S^T formulation, QBLK=64 q-rows PER WAVE (256/block).
//  VERIFIED R6/R9 structure; R10 change: prefetch distance 2 -> 3 on the
//  existing quad-buffer (prologue stages 3 chunks; loop waits vmcnt(8),
//  retiring exactly stage(c) and leaving stage(c+1),(c+2) in flight).
//  WAR safety at distance 3: buffer (c+3)&3 held chunk c-1, whose ds_reads
//  were consumed (compiler lgkmcnt before MFMA issue) before every wave
//  reached barrier(c); the overwriting gld16s issue after barrier(c).
//  All other proven elements unchanged: grid 512 = 2 blocks/CU, u-split
//  chunk body, XOR-swizzled staging (0 bank conflicts), no-max log2-domain
//  softmax, fzero C-operand, direct P8 packing, single-b128 PV frag via
//  permuted V^T storage, denominator via ones-MFMA.
// ---------------------------------------------------------------------------
__global__ __launch_bounds__(256, 2) void attn(
    const unsigned short* __restrict__ Qb, const unsigned short* __restrict__ Kb,
    const unsigned short* __restrict__ Vt, unsigned short* __restrict__ Ob) {
    __shared__ __align__(16) unsigned short Ks[4 * 4096];
    __shared__ __align__(16) unsigned short Vs[4 * 4096];

    const int tid = threadIdx.x;
    const int wave = tid >> 6, lane = tid & 63;
    const int quad = lane >> 4, l16 = lane & 15;

    // XCD-chunked bijective swizzle over 512 blocks: XCD k (= flat&7) owns
    // wids [k*64,(k+1)*64) = 8 whole heads.
    const int flat = blockIdx.x;
    const int wid  = (flat & 7) * 64 + (flat >> 3);
    const int qblk = wid & 7, bh = wid >> 3;
    const int b = bh >> 4, h = bh & 15;
    const int q0 = qblk * 256 + wave * 64;

    const unsigned short* Qp = Qb + (size_t)bh * T_ * HD_;
    const unsigned short* Kp = Kb + (size_t)bh * T_ * HD_;
    const unsigned short* Vp = Vt + (size_t)bh * HD_ * T_;

    // Q as x32 B-operand: B[k=d=ds*32+quad*8+j][n=q=l16]
    s16x8 qf[4][2];
    for (int qt = 0; qt < 4; ++qt)
        for (int ds = 0; ds < 2; ++ds)
            qf[qt][ds] = *(const s16x8*)(Qp + (size_t)(q0 + qt * 16 + l16) * HD_ + ds * 32 + quad * 8);

    f32x4 accO[4][4] = {};             // O^T[d=dt*16+quad*4+r][q=qt*16+l16]
    f32x4 accL[4] = {};                // l[q]: all regs/rows identical
    const f32x4 fzero = {0.f, 0.f, 0.f, 0.f};

    const s16x8 ones = {0x3F80, 0x3F80, 0x3F80, 0x3F80,
                        0x3F80, 0x3F80, 0x3F80, 0x3F80};   // bf16 1.0 x8

    // staging slots: S0=tid, S1=tid+256; r=S>>3, swizzled chunk c=S&7,
    // global chunk cg = c ^ (r&7)
    const int r0 = tid >> 3,           cg0 = (tid & 7) ^ (r0 & 7);
    const int r1 = (tid + 256) >> 3,   cg1 = (tid & 7) ^ (r1 & 7);

    const unsigned short* kp0 = Kp + (size_t)r0 * HD_ + cg0 * 8;
    const unsigned short* kp1 = Kp + (size_t)r1 * HD_ + cg1 * 8;
    const unsigned short* vp0 = Vp + (size_t)r0 * T_ + cg0 * 8;
    const unsigned short* vp1 = Vp + (size_t)r1 * T_ + cg1 * 8;

    unsigned short* dK0 = Ks + tid * 8;
    unsigned short* dV0 = Vs + tid * 8;

    // lane-constant swizzled read offsets (shorts)
    const int xk   = quad ^ (l16 & 7);                      // K kf0 chunk
    const int kro  = l16 * 64 + xk * 8;                     // + kt*1024 imm
    const int kro1 = l16 * 64 + (xk ^ 4) * 8;
    const int vro0 = l16 * 64 + ((quad)     ^ (l16 & 7)) * 8;  // u=0, + dt*1024
    const int vro1 = l16 * 64 + ((4 + quad) ^ (l16 & 7)) * 8;  // u=1

    auto STAGE = [&](int bufi) {
        gld16(kp0, dK0 + bufi * 4096);  gld16(kp1, dK0 + bufi * 4096 + 2048);
        gld16(vp0, dV0 + bufi * 4096);  gld16(vp1, dV0 + bufi * 4096 + 2048);
        kp0 += 64 * HD_; kp1 += 64 * HD_; vp0 += 64; vp1 += 64;
    };

    auto CHUNK = [&](int bufi) {
        const unsigned short* Kc = Ks + bufi * 4096;
        const unsigned short* Vc = Vs + bufi * 4096;
#pragma unroll
        for (int u = 0; u < 2; ++u) {
            // S^T[key][q] for 32 keys: A = K rows (swizzled b128), B = Q regs
            f32x4 st[4][2];
            __builtin_amdgcn_s_setprio(1);
#pragma unroll
            for (int kt2 = 0; kt2 < 2; ++kt2) {
                const int kt = 2 * u + kt2;
                s16x8 kf0 = *(const s16x8*)(Kc + kt * 1024 + kro);
                s16x8 kf1 = *(const s16x8*)(Kc + kt * 1024 + kro1);
                for (int qt = 0; qt < 4; ++qt) {
                    st[qt][kt2] = mfma32(kf0, qf[qt][0], fzero);
                    st[qt][kt2] = mfma32(kf1, qf[qt][1], st[qt][kt2]);
                }
            }
            __builtin_amdgcn_s_setprio(0);
            // no-max softmax -> x32 B-frag: reg j -> key 32u+16*(j>=4)+4quad+(j&3)
            s16x8 pf[4];
            for (int qt = 0; qt < 4; ++qt) {
                P8 pk;
#pragma unroll
                for (int kt2 = 0; kt2 < 2; ++kt2) {
                    f32x4 s = st[qt][kt2];
                    float p0 = __builtin_amdgcn_exp2f(s[0]);
                    float p1 = __builtin_amdgcn_exp2f(s[1]);
                    float p2 = __builtin_amdgcn_exp2f(s[2]);
                    float p3 = __builtin_amdgcn_exp2f(s[3]);
                    pk.w[2 * kt2]     = pk_bf16(p0, p1);
                    pk.w[2 * kt2 + 1] = pk_bf16(p2, p3);
                }
                pf[qt] = pk.v;
            }
            // O^T += V^T @ P^T; l += ones^T @ P^T.  One b128 A-frag per dt.
            __builtin_amdgcn_s_setprio(1);
            for (int qt = 0; qt < 4; ++qt)
                accL[qt] = mfma32(ones, pf[qt], accL[qt]);
            const int vro = (u == 0) ? vro0 : vro1;
            for (int dt = 0; dt < 4; ++dt) {
                s16x8 vf = *(const s16x8*)(Vc + vro + dt * 1024);
                for (int qt = 0; qt < 4; ++qt)
                    accO[qt][dt] = mfma32(vf, pf[qt], accO[qt][dt]);
            }
            __builtin_amdgcn_s_setprio(0);
        }
    };

    STAGE(0);
    STAGE(1);
    STAGE(2);

    // main: chunks 0..27 (7 macro-iters x 4, buffer indices compile-time);
    // distance-3 prefetch: stage chunk c+3 while computing chunk c.
#pragma nounroll
    for (int cc = 0; cc < 28; cc += 4) {
#pragma unroll
        for (int k = 0; k < 4; ++k) {
            asm volatile("s_waitcnt vmcnt(8)" ::: "memory");
            __builtin_amdgcn_s_barrier();
            STAGE((k + 3) & 3);
            CHUNK(k);
        }
    }
    // peeled tail: chunks 28..31 (stage(31) issued at chunk 28)
    asm volatile("s_waitcnt vmcnt(8)" ::: "memory");
    __builtin_amdgcn_s_barrier();
    STAGE(3); CHUNK(0);
    asm volatile("s_waitcnt vmcnt(8)" ::: "memory");
    __builtin_amdgcn_s_barrier();
    CHUNK(1);
    asm volatile("s_waitcnt vmcnt(4)" ::: "memory");
    __builtin_amdgcn_s_barrier();
    CHUNK(2);
    asm volatile("s_waitcnt vmcnt(0)" ::: "memory");
    __builtin_amdgcn_s_barrier();
    CHUNK(3);

    // epilogue: l already fully reduced by the ones-MFMA; store O^T
    for (int qt = 0; qt < 4; ++qt) {
        float inv = 1.f / accL[qt][0];
        int t = q0 + qt * 16 + l16;
        for (int dt = 0; dt < 4; ++dt) {
            U4 o;
            o.w[0] = pk_bf16(accO[qt][dt][0] * inv, accO[qt][dt][1] * inv);
            o.w[1] = pk_bf16(accO[qt][dt][2] * inv, accO[qt][dt][3] * inv);
            *(u16x4*)(Ob + ((size_t)b * T_ + t) * D_ + h * 64 + dt * 16 + quad * 4) = o.v;
        }
    }
}

// ---------------------------------------------------------------------------
extern "C" void kernel_launch(void* const* d_in, const int* in_sizes, int n_in,
                              void* d_out, int out_size, void* d_ws, size_t ws_size,
                              hipStream_t stream) {
    const float* x  = (const float*)d_in[0];
    const float* Wq = (const float*)d_in[1];
    const float* bq = (const float*)d_in[2];
    const float* Wk = (const float*)d_in[3];
    const float* bk = (const float*)d_in[4];
    const float* Wv = (const float*)d_in[5];
    const float* bv = (const float*)d_in[6];
    const float* Wo = (const float*)d_in[7];
    const float* bo = (const float*)d_in[8];
    float* out = (float*)d_out;

    // workspace: xb/Ob(16M) | Qb | Kb | Vbt (16M each) | Wcat (8M) = 72MB
    const size_t SZ = (size_t)M_ * D_ * sizeof(unsigned short);
    unsigned short* xb   = (unsigned short*)d_ws;
    unsigned short* Qb   = (unsigned short*)((char*)d_ws + 1 * SZ);
    unsigned short* Kb   = (unsigned short*)((char*)d_ws + 2 * SZ);
    unsigned short* Vbt  = (unsigned short*)((char*)d_ws + 3 * SZ);
    unsigned short* Wcat = (unsigned short*)((char*)d_ws + 4 * SZ);
    unsigned short* Ob   = xb;  // xb dead after QKV GEMM

    const float qscale = 1.4426950408889634f / 8.0f;  // log2(e)/sqrt(HD)

    dim3 blk(256);
    cvt_all<<<dim3(6144), blk, 0, stream>>>(x, Wq, Wk, Wv, Wo, xb, Wcat);
    gemm_qkv<<<dim3(1536), blk, 0, stream>>>(xb, Wcat, bq, bk, bv, Qb, Kb, Vbt, qscale);
    attn<<<dim3(512), blk, 0, stream>>>(Qb, Kb, Vbt, Ob);
    gemm_o<<<dim3(512), blk, 0, stream>>>(Ob, Wcat + 3 * 1048576, bo, out);
}